// Round 3
// baseline (198.653 us; speedup 1.0000x reference)
//
#include <hip/hip_runtime.h>
#include <math.h>

#define N_ROWS 4096
#define D_DIM  256
#define INV_T  (1.0f / 0.07f)
#define NW     (N_ROWS / 64)          // 64 packed u64 words per mask row

typedef _Float16 half8 __attribute__((ext_vector_type(8)));
typedef _Float16 half4 __attribute__((ext_vector_type(4)));
typedef float    f32x4 __attribute__((ext_vector_type(4)));
typedef unsigned long long u64;

#define GLOAD_LDS(gp, lp) \
    __builtin_amdgcn_global_load_lds( \
        (const __attribute__((address_space(1))) void*)(gp), \
        (__attribute__((address_space(3))) void*)(lp), 16, 0, 0)

// ---------------------------------------------------------------------------
// prep_k: merged (a) row-normalize features -> fp16, (b) mask compress to
// bits, (c) accum zeroing.  One wave per row.
// Mask reads are the ONLY place the 128 MB of pm/nm is touched: scalar
// float per lane = 256 B contiguous per wave-instruction, sequentially
// advancing -> DRAM-friendly streaming.  unroll 8 keeps 16 loads in flight
// per wave.  Diagonal (col==row) is folded into the bits here.
// ---------------------------------------------------------------------------
__global__ __launch_bounds__(256) void prep_k(const float* __restrict__ f,
                                              const float* __restrict__ pm,
                                              const float* __restrict__ nm,
                                              _Float16* __restrict__ fnh,
                                              u64* __restrict__ P,
                                              u64* __restrict__ N,
                                              float* __restrict__ accum) {
    const int t   = threadIdx.x;
    const int gid = blockIdx.x * 256 + t;
    if (gid < 3 * N_ROWS) accum[gid] = 0.0f;

    const int lane = t & 63;
    const int row  = blockIdx.x * 4 + (t >> 6);

    // ---- normalize ----
    float4 v = ((const float4*)(f + (size_t)row * D_DIM))[lane];
    float s = v.x * v.x + v.y * v.y + v.z * v.z + v.w * v.w;
    #pragma unroll
    for (int off = 32; off > 0; off >>= 1) s += __shfl_xor(s, off, 64);
    float rn = 1.0f / fmaxf(sqrtf(s), 1e-8f);
    half4 h;
    h.x = (_Float16)(v.x * rn);
    h.y = (_Float16)(v.y * rn);
    h.z = (_Float16)(v.z * rn);
    h.w = (_Float16)(v.w * rn);
    *(half4*)(fnh + (size_t)row * D_DIM + lane * 4) = h;

    // ---- mask compress: 64 ballot rounds cover the 4096-col row ----
    const float* pr = pm + (size_t)row * N_ROWS;
    const float* nr = nm + (size_t)row * N_ROWS;
    u64 myP = 0, myN = 0;
    #pragma unroll 8
    for (int r = 0; r < 64; ++r) {
        const int col = r * 64 + lane;
        const float pv = pr[col];
        const float nv = nr[col];
        const u64 bp = __ballot(pv != 0.0f && col != row);
        const u64 bn = __ballot(nv != 0.0f && col != row);
        if (lane == r) { myP = bp; myN = bn; }
    }
    P[(size_t)row * NW + lane] = myP;   // coalesced 512 B per wave
    N[(size_t)row * NW + lane] = myN;
}

// ---------------------------------------------------------------------------
// fused_k (v10): identical GEMM core to the verified round-9 kernel, but
// masks come from the packed bit arrays: 4 x u64 loads per thread (2 rows
// x {P,N}), prefetched before the K-loop, nibble-extracted after the first
// barrier.  Mask HBM traffic per launch: 4 MB instead of 128 MB.
// ---------------------------------------------------------------------------
__global__ __launch_bounds__(256) void fused_k(const _Float16* __restrict__ fnh,
                                               const u64* __restrict__ P,
                                               const u64* __restrict__ N,
                                               float* __restrict__ accum) {
    __shared__ __align__(16) _Float16 lds[64 * 128];   // 16 KB
    _Float16* As = lds;             // [64][64] halfs during K-loop
    _Float16* Bs = lds + 64 * 64;   // [64][64] halfs during K-loop

    const int t    = threadIdx.x;
    const int lane = t & 63;
    const int w    = t >> 6;        // wave 0..3
    const int wr   = w >> 1;        // i-half of tile
    const int wc   = w & 1;         // j-half of tile
    const int i0   = blockIdx.y * 64;
    const int j0   = blockIdx.x * 64;
    const int l15  = lane & 15;
    const int grp  = lane >> 4;

    const int srow  = t >> 3;
    const int sslot = ((t & 7) ^ ((t >> 3) & 7)) * 8;

    // ---- packed-mask prefetch: rides under the whole GEMM ----
    const int mrow0 = i0 + wr * 32 + l15;
    const int jw    = blockIdx.x;           // j-window = exactly one u64
    u64 wp[2], wn[2];
    #pragma unroll
    for (int it = 0; it < 2; ++it) {
        const size_t o = (size_t)(mrow0 + it * 16) * NW + jw;
        wp[it] = P[o];
        wn[it] = N[o];
    }

    f32x4 acc[2][2];  // [jt][it]
    #pragma unroll
    for (int a = 0; a < 2; ++a)
        #pragma unroll
        for (int b = 0; b < 2; ++b)
            acc[a][b] = (f32x4){0.f, 0.f, 0.f, 0.f};

    unsigned pmb = 0, nmb = 0;   // 16 bits each: b = it*8 + jt*4 + e

    #pragma unroll
    for (int k0 = 0; k0 < D_DIM; k0 += 64) {
        #pragma unroll
        for (int q = 0; q < 2; ++q) {
            GLOAD_LDS(fnh + (size_t)(i0 + q * 32 + srow) * D_DIM + k0 + sslot,
                      &As[q * 2048 + w * 512]);
            GLOAD_LDS(fnh + (size_t)(j0 + q * 32 + srow) * D_DIM + k0 + sslot,
                      &Bs[q * 2048 + w * 512]);
        }
        __syncthreads();   // drains staging AND (first iter) the mask loads

        if (k0 == 0) {
            #pragma unroll
            for (int it = 0; it < 2; ++it)
                #pragma unroll
                for (int jt = 0; jt < 2; ++jt) {
                    const int sh = wc * 32 + jt * 16 + grp * 4;
                    pmb |= ((unsigned)((wp[it] >> sh) & 0xFull)) << (it * 8 + jt * 4);
                    nmb |= ((unsigned)((wn[it] >> sh) & 0xFull)) << (it * 8 + jt * 4);
                }
        }

        #pragma unroll
        for (int kk = 0; kk < 2; ++kk) {
            half8 aj[2], bi[2];
            #pragma unroll
            for (int jt = 0; jt < 2; ++jt) {
                const int r = wc * 32 + jt * 16 + l15;
                aj[jt] = *(const half8*)&Bs[r * 64 + (((kk * 4 + grp) ^ (r & 7)) << 3)];
            }
            #pragma unroll
            for (int it = 0; it < 2; ++it) {
                const int r = wr * 32 + it * 16 + l15;
                bi[it] = *(const half8*)&As[r * 64 + (((kk * 4 + grp) ^ (r & 7)) << 3)];
            }
            #pragma unroll
            for (int jt = 0; jt < 2; ++jt)
                #pragma unroll
                for (int it = 0; it < 2; ++it)
                    acc[jt][it] = __builtin_amdgcn_mfma_f32_16x16x32_f16(
                        aj[jt], bi[it], acc[jt][it], 0, 0, 0);
        }
        __syncthreads();
    }

    // ---- epilogue: streaming from registers, butterfly over grp ----
    #pragma unroll
    for (int it = 0; it < 2; ++it) {
        float negp = 0.f, posp = 0.f, np = 0.f;
        #pragma unroll
        for (int jt = 0; jt < 2; ++jt)
            #pragma unroll
            for (int e = 0; e < 4; ++e) {
                const int b = it * 8 + jt * 4 + e;
                const float cs = acc[jt][it][e] * INV_T;
                const float pf = (float)((pmb >> b) & 1u);
                const float nf = (float)((nmb >> b) & 1u);
                negp = fmaf(__expf(cs), nf, negp);
                posp = fmaf(cs, pf, posp);
                np  += pf;
            }
        #pragma unroll
        for (int off = 16; off < 64; off <<= 1) {
            negp += __shfl_xor(negp, off, 64);
            posp += __shfl_xor(posp, off, 64);
            np   += __shfl_xor(np,   off, 64);
        }
        if (grp == 0) {
            const int i = mrow0 + it * 16;
            atomicAdd(&accum[i], negp);
            atomicAdd(&accum[N_ROWS + i], posp);
            atomicAdd(&accum[2 * N_ROWS + i], np);
        }
    }
}

// ---------------------------------------------------------------------------
// Fallback path (verified round-9 kernels), used only if ws_size is too
// small for the packed-mask layout.
// ---------------------------------------------------------------------------
__global__ __launch_bounds__(256) void normalize_k(const float* __restrict__ f,
                                                   _Float16* __restrict__ fnh,
                                                   float* __restrict__ accum) {
    const int t   = threadIdx.x;
    const int gid = blockIdx.x * 256 + t;
    if (gid < 3 * N_ROWS) accum[gid] = 0.0f;

    const int lane = t & 63;
    const int row  = blockIdx.x * 4 + (t >> 6);
    float4 v = ((const float4*)(f + (size_t)row * D_DIM))[lane];
    float s = v.x * v.x + v.y * v.y + v.z * v.z + v.w * v.w;
    #pragma unroll
    for (int off = 32; off > 0; off >>= 1) s += __shfl_xor(s, off, 64);
    float rn = 1.0f / fmaxf(sqrtf(s), 1e-8f);
    half4 h;
    h.x = (_Float16)(v.x * rn);
    h.y = (_Float16)(v.y * rn);
    h.z = (_Float16)(v.z * rn);
    h.w = (_Float16)(v.w * rn);
    *(half4*)(fnh + (size_t)row * D_DIM + lane * 4) = h;
}

__global__ __launch_bounds__(256) void fused_v9(const _Float16* __restrict__ fnh,
                                                const float* __restrict__ pm,
                                                const float* __restrict__ nm,
                                                float* __restrict__ accum) {
    __shared__ __align__(16) _Float16 lds[64 * 128];
    _Float16* As = lds;
    _Float16* Bs = lds + 64 * 64;

    const int t    = threadIdx.x;
    const int lane = t & 63;
    const int w    = t >> 6;
    const int wr   = w >> 1;
    const int wc   = w & 1;
    const int i0   = blockIdx.y * 64;
    const int j0   = blockIdx.x * 64;
    const int l15  = lane & 15;
    const int grp  = lane >> 4;

    const int srow  = t >> 3;
    const int sslot = ((t & 7) ^ ((t >> 3) & 7)) * 8;

    const int mrow0 = i0 + wr * 32 + l15;
    const int mcol0 = j0 + wc * 32 + grp * 4;
    float4 pmv[2][2], nmv[2][2];
    #pragma unroll
    for (int it = 0; it < 2; ++it)
        #pragma unroll
        for (int jt = 0; jt < 2; ++jt) {
            const size_t off = (size_t)(mrow0 + it * 16) * N_ROWS + (mcol0 + jt * 16);
            pmv[it][jt] = *(const float4*)(pm + off);
            nmv[it][jt] = *(const float4*)(nm + off);
        }

    f32x4 acc[2][2];
    #pragma unroll
    for (int a = 0; a < 2; ++a)
        #pragma unroll
        for (int b = 0; b < 2; ++b)
            acc[a][b] = (f32x4){0.f, 0.f, 0.f, 0.f};

    unsigned pmb = 0, nmb = 0;

    #pragma unroll
    for (int k0 = 0; k0 < D_DIM; k0 += 64) {
        #pragma unroll
        for (int q = 0; q < 2; ++q) {
            GLOAD_LDS(fnh + (size_t)(i0 + q * 32 + srow) * D_DIM + k0 + sslot,
                      &As[q * 2048 + w * 512]);
            GLOAD_LDS(fnh + (size_t)(j0 + q * 32 + srow) * D_DIM + k0 + sslot,
                      &Bs[q * 2048 + w * 512]);
        }
        __syncthreads();

        if (k0 == 0) {
            #pragma unroll
            for (int it = 0; it < 2; ++it)
                #pragma unroll
                for (int jt = 0; jt < 2; ++jt) {
                    const int i = mrow0 + it * 16;
                    const int jb = mcol0 + jt * 16;
                    float pe[4] = {pmv[it][jt].x, pmv[it][jt].y,
                                   pmv[it][jt].z, pmv[it][jt].w};
                    float ne[4] = {nmv[it][jt].x, nmv[it][jt].y,
                                   nmv[it][jt].z, nmv[it][jt].w};
                    #pragma unroll
                    for (int e = 0; e < 4; ++e) {
                        const int b = it * 8 + jt * 4 + e;
                        const unsigned keep = (unsigned)(i != (jb + e));
                        pmb |= (((unsigned)(pe[e] != 0.f) & keep) << b);
                        nmb |= (((unsigned)(ne[e] != 0.f) & keep) << b);
                    }
                }
        }

        #pragma unroll
        for (int kk = 0; kk < 2; ++kk) {
            half8 aj[2], bi[2];
            #pragma unroll
            for (int jt = 0; jt < 2; ++jt) {
                const int r = wc * 32 + jt * 16 + l15;
                aj[jt] = *(const half8*)&Bs[r * 64 + (((kk * 4 + grp) ^ (r & 7)) << 3)];
            }
            #pragma unroll
            for (int it = 0; it < 2; ++it) {
                const int r = wr * 32 + it * 16 + l15;
                bi[it] = *(const half8*)&As[r * 64 + (((kk * 4 + grp) ^ (r & 7)) << 3)];
            }
            #pragma unroll
            for (int jt = 0; jt < 2; ++jt)
                #pragma unroll
                for (int it = 0; it < 2; ++it)
                    acc[jt][it] = __builtin_amdgcn_mfma_f32_16x16x32_f16(
                        aj[jt], bi[it], acc[jt][it], 0, 0, 0);
        }
        __syncthreads();
    }

    #pragma unroll
    for (int it = 0; it < 2; ++it) {
        float negp = 0.f, posp = 0.f, np = 0.f;
        #pragma unroll
        for (int jt = 0; jt < 2; ++jt)
            #pragma unroll
            for (int e = 0; e < 4; ++e) {
                const int b = it * 8 + jt * 4 + e;
                const float cs = acc[jt][it][e] * INV_T;
                const float pf = (float)((pmb >> b) & 1u);
                const float nf = (float)((nmb >> b) & 1u);
                negp = fmaf(__expf(cs), nf, negp);
                posp = fmaf(cs, pf, posp);
                np  += pf;
            }
        #pragma unroll
        for (int off = 16; off < 64; off <<= 1) {
            negp += __shfl_xor(negp, off, 64);
            posp += __shfl_xor(posp, off, 64);
            np   += __shfl_xor(np,   off, 64);
        }
        if (grp == 0) {
            const int i = mrow0 + it * 16;
            atomicAdd(&accum[i], negp);
            atomicAdd(&accum[N_ROWS + i], posp);
            atomicAdd(&accum[2 * N_ROWS + i], np);
        }
    }
}

// ---------------------------------------------------------------------------
// final_k: reduction over rows -> scalar loss
// ---------------------------------------------------------------------------
__global__ __launch_bounds__(256) void final_k(const float* __restrict__ accum,
                                               float* __restrict__ out) {
    const int t = threadIdx.x;
    float s = 0.f;
    for (int i = t; i < N_ROWS; i += 256) {
        float neg  = accum[i];
        float posc = accum[N_ROWS + i];
        float np   = accum[2 * N_ROWS + i];
        float term = (np > 0.f) ? (posc - np * logf(fmaxf(neg, 1e-30f))) / np : 0.f;
        s += term;
    }
    #pragma unroll
    for (int off = 32; off > 0; off >>= 1) s += __shfl_xor(s, off, 64);
    __shared__ float wsum[4];
    if ((t & 63) == 0) wsum[t >> 6] = s;
    __syncthreads();
    if (t == 0) {
        float tot = wsum[0] + wsum[1] + wsum[2] + wsum[3];
        out[0] = -tot / (float)N_ROWS;
    }
}

// ---------------------------------------------------------------------------
extern "C" void kernel_launch(void* const* d_in, const int* in_sizes, int n_in,
                              void* d_out, int out_size, void* d_ws, size_t ws_size,
                              hipStream_t stream) {
    const float* feat = (const float*)d_in[0];
    const float* pm   = (const float*)d_in[1];
    const float* nm   = (const float*)d_in[2];
    float* out = (float*)d_out;

    const size_t FNH_B   = (size_t)N_ROWS * D_DIM * sizeof(_Float16);  // 2 MB
    const size_t ACC_B   = 65536;                                      // 48 KB used
    const size_t PACK_B  = (size_t)N_ROWS * NW * sizeof(u64);          // 2 MB each
    const size_t NEEDED  = FNH_B + ACC_B + 2 * PACK_B;                 // ~6.2 MB

    _Float16* fnh = (_Float16*)d_ws;
    float* accum  = (float*)((char*)d_ws + FNH_B);

    if (ws_size >= NEEDED) {
        u64* P = (u64*)((char*)d_ws + FNH_B + ACC_B);
        u64* N = (u64*)((char*)d_ws + FNH_B + ACC_B + PACK_B);

        prep_k<<<N_ROWS / 4, 256, 0, stream>>>(feat, pm, nm, fnh, P, N, accum);

        dim3 grid(N_ROWS / 64, N_ROWS / 64);
        fused_k<<<grid, 256, 0, stream>>>(fnh, P, N, accum);
    } else {
        normalize_k<<<N_ROWS / 4, 256, 0, stream>>>(feat, fnh, accum);
        dim3 grid(N_ROWS / 64, N_ROWS / 64);
        fused_v9<<<grid, 256, 0, stream>>>(fnh, pm, nm, accum);
    }

    final_k<<<1, 256, 0, stream>>>(accum, out);
}

// Round 5
// 191.202 us; speedup vs baseline: 1.0390x; 1.0390x over previous
//
#include <hip/hip_runtime.h>
#include <math.h>

#define N_ROWS 4096
#define D_DIM  256
#define INV_T  (1.0f / 0.07f)
#define NW     (N_ROWS / 64)          // 64 packed u64 words per mask row

typedef _Float16 half8 __attribute__((ext_vector_type(8)));
typedef _Float16 half4 __attribute__((ext_vector_type(4)));
typedef float    f32x4 __attribute__((ext_vector_type(4)));
typedef unsigned long long u64;

#define GLOAD_LDS(gp, lp) \
    __builtin_amdgcn_global_load_lds( \
        (const __attribute__((address_space(1))) void*)(gp), \
        (__attribute__((address_space(3))) void*)(lp), 16, 0, 0)

// ---------------------------------------------------------------------------
// prep_k v2: normalize + mask-compress + accum zero.  One wave per row.
// Round-3 post-mortem: v1 streamed masks at 4 B/lane scalar -> 2.6 TB/s
// (the known scalar-load regime).  v2 loads float4 (16 B/lane) and uses a
// nibble-per-lane packed layout requiring NO cross-lane ops:
//   lane L, chunk c (cols 256c+4L+e, e=0..3) -> nibble at bits [4c,4c+3]
//   of u64 stored at P[row*64 + L].
// Diagonal (col==row) folded in here.  Stores 512 B contiguous per wave.
// (Round 4 was an infra failure; this is a verbatim resubmission.)
// ---------------------------------------------------------------------------
__global__ __launch_bounds__(256) void prep_k(const float* __restrict__ f,
                                              const float* __restrict__ pm,
                                              const float* __restrict__ nm,
                                              _Float16* __restrict__ fnh,
                                              u64* __restrict__ P,
                                              u64* __restrict__ N,
                                              float* __restrict__ accum) {
    const int t   = threadIdx.x;
    const int gid = blockIdx.x * 256 + t;
    if (gid < 3 * N_ROWS) accum[gid] = 0.0f;

    const int lane = t & 63;
    const int row  = blockIdx.x * 4 + (t >> 6);

    // ---- normalize ----
    float4 v = ((const float4*)(f + (size_t)row * D_DIM))[lane];
    float s = v.x * v.x + v.y * v.y + v.z * v.z + v.w * v.w;
    #pragma unroll
    for (int off = 32; off > 0; off >>= 1) s += __shfl_xor(s, off, 64);
    float rn = 1.0f / fmaxf(sqrtf(s), 1e-8f);
    half4 h;
    h.x = (_Float16)(v.x * rn);
    h.y = (_Float16)(v.y * rn);
    h.z = (_Float16)(v.z * rn);
    h.w = (_Float16)(v.w * rn);
    *(half4*)(fnh + (size_t)row * D_DIM + lane * 4) = h;

    // ---- mask compress: 16 chunks x (2 x float4 loads), no cross-lane ----
    const float* pr = pm + (size_t)row * N_ROWS;
    const float* nr = nm + (size_t)row * N_ROWS;
    u64 myP = 0, myN = 0;
    #pragma unroll 8
    for (int c = 0; c < 16; ++c) {
        const int col0 = c * 256 + lane * 4;
        float4 pv = *(const float4*)(pr + col0);
        float4 nv = *(const float4*)(nr + col0);
        float pe[4] = {pv.x, pv.y, pv.z, pv.w};
        float ne[4] = {nv.x, nv.y, nv.z, nv.w};
        unsigned nibP = 0, nibN = 0;
        #pragma unroll
        for (int e = 0; e < 4; ++e) {
            const unsigned keep = (unsigned)(col0 + e != row);
            nibP |= (((unsigned)(pe[e] != 0.f) & keep) << e);
            nibN |= (((unsigned)(ne[e] != 0.f) & keep) << e);
        }
        myP |= ((u64)nibP) << (4 * c);
        myN |= ((u64)nibN) << (4 * c);
    }
    P[(size_t)row * NW + lane] = myP;
    N[(size_t)row * NW + lane] = myN;
}

// ---------------------------------------------------------------------------
// fused_k v11: 128x128 tile GEMM (m93 structure: 4 waves, each 64x64 via
// 4x4 fragments of 16x16x32; 32 MFMA : 16 ds_read_b128 per K-step) + packed
// mask epilogue.  Grid 32x32.  LDS 32 KB.  Swizzle formulas identical to
// the verified 64-tile kernel (rows are still 64 halfs wide).
// Mask words (L2-resident, 4 MB total) loaded in the epilogue:
//   col = bx*128 + wc*64 + jt*16 + grp*4 + e
//   word index L = (bx&1)*32 + wc*16 + jt*4 + grp, nibble c = bx>>1, bit e.
// ---------------------------------------------------------------------------
__global__ __launch_bounds__(256) void fused_k(const _Float16* __restrict__ fnh,
                                               const u64* __restrict__ P,
                                               const u64* __restrict__ N,
                                               float* __restrict__ accum) {
    __shared__ __align__(16) _Float16 lds[2 * 128 * 64];   // 32 KB
    _Float16* As = lds;               // [128][64]
    _Float16* Bs = lds + 128 * 64;    // [128][64]

    const int t    = threadIdx.x;
    const int lane = t & 63;
    const int w    = t >> 6;        // wave 0..3
    const int wr   = w >> 1;        // i-half (64 rows)
    const int wc   = w & 1;         // j-half (64 cols)
    const int bx   = blockIdx.x;
    const int i0   = blockIdx.y * 128;
    const int j0   = bx * 128;
    const int l15  = lane & 15;
    const int grp  = lane >> 4;

    const int srow  = t >> 3;                          // 0..31
    const int sslot = ((t & 7) ^ ((t >> 3) & 7)) * 8;  // swizzled granule

    f32x4 acc[4][4];  // [jt][it]
    #pragma unroll
    for (int a = 0; a < 4; ++a)
        #pragma unroll
        for (int b = 0; b < 4; ++b)
            acc[a][b] = (f32x4){0.f, 0.f, 0.f, 0.f};

    for (int k0 = 0; k0 < D_DIM; k0 += 64) {
        #pragma unroll
        for (int q = 0; q < 4; ++q) {
            GLOAD_LDS(fnh + (size_t)(i0 + q * 32 + srow) * D_DIM + k0 + sslot,
                      &As[q * 2048 + w * 512]);
            GLOAD_LDS(fnh + (size_t)(j0 + q * 32 + srow) * D_DIM + k0 + sslot,
                      &Bs[q * 2048 + w * 512]);
        }
        __syncthreads();

        #pragma unroll
        for (int kk = 0; kk < 2; ++kk) {
            half8 aj[4], bi[4];
            #pragma unroll
            for (int jt = 0; jt < 4; ++jt) {
                const int r = wc * 64 + jt * 16 + l15;
                aj[jt] = *(const half8*)&Bs[r * 64 + (((kk * 4 + grp) ^ (r & 7)) << 3)];
            }
            #pragma unroll
            for (int it = 0; it < 4; ++it) {
                const int r = wr * 64 + it * 16 + l15;
                bi[it] = *(const half8*)&As[r * 64 + (((kk * 4 + grp) ^ (r & 7)) << 3)];
            }
            #pragma unroll
            for (int jt = 0; jt < 4; ++jt)
                #pragma unroll
                for (int it = 0; it < 4; ++it)
                    acc[jt][it] = __builtin_amdgcn_mfma_f32_16x16x32_f16(
                        aj[jt], bi[it], acc[jt][it], 0, 0, 0);
        }
        __syncthreads();
    }

    // ---- epilogue: packed-mask loads (L2), exp/fma, reduce over grp ----
    const int mrow0 = i0 + wr * 64 + l15;
    const int Lb    = (bx & 1) * 32 + wc * 16 + grp;   // + jt*4
    const int csh   = (bx >> 1) * 4;                   // nibble shift

    #pragma unroll
    for (int it = 0; it < 4; ++it) {
        const int i = mrow0 + it * 16;
        float negp = 0.f, posp = 0.f, np = 0.f;
        #pragma unroll
        for (int jt = 0; jt < 4; ++jt) {
            const u64 wpv = P[(size_t)i * NW + Lb + jt * 4];
            const u64 wnv = N[(size_t)i * NW + Lb + jt * 4];
            const unsigned nibP = (unsigned)(wpv >> csh) & 0xFu;
            const unsigned nibN = (unsigned)(wnv >> csh) & 0xFu;
            #pragma unroll
            for (int e = 0; e < 4; ++e) {
                const float cs = acc[jt][it][e] * INV_T;
                const float pf = (float)((nibP >> e) & 1u);
                const float nf = (float)((nibN >> e) & 1u);
                negp = fmaf(__expf(cs), nf, negp);
                posp = fmaf(cs, pf, posp);
                np  += pf;
            }
        }
        negp += __shfl_xor(negp, 16, 64);
        posp += __shfl_xor(posp, 16, 64);
        np   += __shfl_xor(np,   16, 64);
        negp += __shfl_xor(negp, 32, 64);
        posp += __shfl_xor(posp, 32, 64);
        np   += __shfl_xor(np,   32, 64);
        if (grp == 0) {
            atomicAdd(&accum[i], negp);
            atomicAdd(&accum[N_ROWS + i], posp);
            atomicAdd(&accum[2 * N_ROWS + i], np);
        }
    }
}

// ---------------------------------------------------------------------------
// final_k: reduction over rows -> scalar loss
// ---------------------------------------------------------------------------
__global__ __launch_bounds__(256) void final_k(const float* __restrict__ accum,
                                               float* __restrict__ out) {
    const int t = threadIdx.x;
    float s = 0.f;
    for (int i = t; i < N_ROWS; i += 256) {
        float neg  = accum[i];
        float posc = accum[N_ROWS + i];
        float np   = accum[2 * N_ROWS + i];
        float term = (np > 0.f) ? (posc - np * logf(fmaxf(neg, 1e-30f))) / np : 0.f;
        s += term;
    }
    #pragma unroll
    for (int off = 32; off > 0; off >>= 1) s += __shfl_xor(s, off, 64);
    __shared__ float wsum[4];
    if ((t & 63) == 0) wsum[t >> 6] = s;
    __syncthreads();
    if (t == 0) {
        float tot = wsum[0] + wsum[1] + wsum[2] + wsum[3];
        out[0] = -tot / (float)N_ROWS;
    }
}

// ---------------------------------------------------------------------------
// ws layout: fnh 2 MB | accum 64 KB | P 2 MB | N 2 MB  (~6.2 MB total;
// round-3 profile confirms ws_size is sufficient on this harness).
// ---------------------------------------------------------------------------
extern "C" void kernel_launch(void* const* d_in, const int* in_sizes, int n_in,
                              void* d_out, int out_size, void* d_ws, size_t ws_size,
                              hipStream_t stream) {
    const float* feat = (const float*)d_in[0];
    const float* pm   = (const float*)d_in[1];
    const float* nm   = (const float*)d_in[2];
    float* out = (float*)d_out;

    const size_t FNH_B = (size_t)N_ROWS * D_DIM * sizeof(_Float16);  // 2 MB
    const size_t ACC_B = 65536;

    _Float16* fnh = (_Float16*)d_ws;
    float* accum  = (float*)((char*)d_ws + FNH_B);
    u64* P = (u64*)((char*)d_ws + FNH_B + ACC_B);
    u64* N = (u64*)((char*)d_ws + FNH_B + ACC_B + (size_t)N_ROWS * NW * sizeof(u64));

    prep_k<<<N_ROWS / 4, 256, 0, stream>>>(feat, pm, nm, fnh, P, N, accum);

    dim3 grid(N_ROWS / 128, N_ROWS / 128);
    fused_k<<<grid, 256, 0, stream>>>(fnh, P, N, accum);

    final_k<<<1, 256, 0, stream>>>(accum, out);
}

// Round 6
// 178.973 us; speedup vs baseline: 1.1100x; 1.0683x over previous
//
#include <hip/hip_runtime.h>
#include <math.h>

#define N_ROWS 4096
#define D_DIM  256
#define INV_T  (1.0f / 0.07f)

typedef _Float16 half8 __attribute__((ext_vector_type(8)));
typedef _Float16 half4 __attribute__((ext_vector_type(4)));
typedef float    f32x4 __attribute__((ext_vector_type(4)));
typedef unsigned long long u64;
typedef unsigned char u8;

#define GLOAD_LDS(gp, lp) \
    __builtin_amdgcn_global_load_lds( \
        (const __attribute__((address_space(1))) void*)(gp), \
        (__attribute__((address_space(3))) void*)(lp), 16, 0, 0)

// ---------------------------------------------------------------------------
// prep_k v3: normalize + mask-compress (byte layout) + accum zero.
// Round-5 post-mortem: v2 (float4 loads, 1024 blocks, VGPR=36) still ran at
// 2.75 TB/s with nothing saturated -> concurrency-bound, not width-bound.
// v3 maximizes both concurrency axes:
//   - 2048 blocks (8/CU, 32 waves/CU cap instead of 16)
//   - each wave owns HALF a row (8 chunks of 256 cols); all 16 float4 loads
//     (8 pm + 8 nm) are issued into a register batch before any consumption
//     -> ~16 KB in flight per wave (VGPR ~100, which is free at this
//     occupancy), ~4x v2's in-flight depth.
// Byte-packed layout: M[row][c][perm(lane)], one byte = nibP | nibN<<4 for
// cols {256c + 4*lane + e}.  perm(lane) swaps lane bit-groups so that the
// 4 bytes fused_k needs per (it) are CONTIGUOUS (one u32 load):
//   perm = (lane&0x30) | ((lane&3)<<2) | ((lane>>2)&3)   (bijective in 0..63,
//   stays within one 64-B line -> wave store still covers whole lines).
// Diagonal (col==row) folded in here.
// ---------------------------------------------------------------------------
__global__ __launch_bounds__(256) void prep_k(const float* __restrict__ f,
                                              const float* __restrict__ pm,
                                              const float* __restrict__ nm,
                                              _Float16* __restrict__ fnh,
                                              u8* __restrict__ M,
                                              float* __restrict__ accum) {
    const int t   = threadIdx.x;
    const int b   = blockIdx.x;
    const int gid = b * 256 + t;
    if (gid < 3 * N_ROWS) accum[gid] = 0.0f;

    const int lane = t & 63;
    const int w    = t >> 6;        // wave 0..3
    const int r0   = b * 2;

    // ---- mask compress: wave w -> row r0+(w>>1), chunks (w&1)*8 .. +8 ----
    const int row = r0 + (w >> 1);
    const int c0  = (w & 1) * 8;
    const float* pr = pm + (size_t)row * N_ROWS;
    const float* nr = nm + (size_t)row * N_ROWS;

    float4 pv[8], nv[8];
    #pragma unroll
    for (int q = 0; q < 8; ++q) {
        const int col0 = (c0 + q) * 256 + lane * 4;
        pv[q] = *(const float4*)(pr + col0);
        nv[q] = *(const float4*)(nr + col0);
    }

    // ---- normalize rides under the mask-load latency: waves 0,1 only ----
    if (w < 2) {
        const int nrow = r0 + w;
        float4 v = ((const float4*)(f + (size_t)nrow * D_DIM))[lane];
        float s = v.x * v.x + v.y * v.y + v.z * v.z + v.w * v.w;
        #pragma unroll
        for (int off = 32; off > 0; off >>= 1) s += __shfl_xor(s, off, 64);
        float rn = 1.0f / fmaxf(sqrtf(s), 1e-8f);
        half4 h;
        h.x = (_Float16)(v.x * rn);
        h.y = (_Float16)(v.y * rn);
        h.z = (_Float16)(v.z * rn);
        h.w = (_Float16)(v.w * rn);
        *(half4*)(fnh + (size_t)nrow * D_DIM + lane * 4) = h;
    }

    const int perm = (lane & 0x30) | ((lane & 3) << 2) | ((lane >> 2) & 3);
    #pragma unroll
    for (int q = 0; q < 8; ++q) {
        const int c    = c0 + q;
        const int col0 = c * 256 + lane * 4;
        float pe[4] = {pv[q].x, pv[q].y, pv[q].z, pv[q].w};
        float ne[4] = {nv[q].x, nv[q].y, nv[q].z, nv[q].w};
        unsigned bytev = 0;
        #pragma unroll
        for (int e = 0; e < 4; ++e) {
            const unsigned keep = (unsigned)(col0 + e != row);
            bytev |= (((unsigned)(pe[e] != 0.f) & keep) << e);
            bytev |= (((unsigned)(ne[e] != 0.f) & keep) << (4 + e));
        }
        M[(size_t)row * 1024 + c * 64 + perm] = (u8)bytev;
    }
}

// ---------------------------------------------------------------------------
// fused_k v12: 128x128 tile GEMM (m93 structure, verified round-5: 4 waves,
// 4x4 fragments of 16x16x32, 32 KB LDS, grid 32x32) + byte-mask epilogue.
// Mask fetch per thread: ONE u32 per it (4 jt-bytes contiguous thanks to
// prep's perm): addr = M + i*1024 + (bx>>1)*64 + (bx&1)*32 + wc*16 + grp*4.
// Byte jt: bit e = P, bit 4+e = N.  16 B/thread total, M is 4 MB (L2).
// ---------------------------------------------------------------------------
__global__ __launch_bounds__(256) void fused_k(const _Float16* __restrict__ fnh,
                                               const u8* __restrict__ M,
                                               float* __restrict__ accum) {
    __shared__ __align__(16) _Float16 lds[2 * 128 * 64];   // 32 KB
    _Float16* As = lds;               // [128][64]
    _Float16* Bs = lds + 128 * 64;    // [128][64]

    const int t    = threadIdx.x;
    const int lane = t & 63;
    const int w    = t >> 6;        // wave 0..3
    const int wr   = w >> 1;        // i-half (64 rows)
    const int wc   = w & 1;         // j-half (64 cols)
    const int bx   = blockIdx.x;
    const int i0   = blockIdx.y * 128;
    const int j0   = bx * 128;
    const int l15  = lane & 15;
    const int grp  = lane >> 4;

    const int srow  = t >> 3;                          // 0..31
    const int sslot = ((t & 7) ^ ((t >> 3) & 7)) * 8;  // swizzled granule

    f32x4 acc[4][4];  // [jt][it]
    #pragma unroll
    for (int a = 0; a < 4; ++a)
        #pragma unroll
        for (int b = 0; b < 4; ++b)
            acc[a][b] = (f32x4){0.f, 0.f, 0.f, 0.f};

    for (int k0 = 0; k0 < D_DIM; k0 += 64) {
        #pragma unroll
        for (int q = 0; q < 4; ++q) {
            GLOAD_LDS(fnh + (size_t)(i0 + q * 32 + srow) * D_DIM + k0 + sslot,
                      &As[q * 2048 + w * 512]);
            GLOAD_LDS(fnh + (size_t)(j0 + q * 32 + srow) * D_DIM + k0 + sslot,
                      &Bs[q * 2048 + w * 512]);
        }
        __syncthreads();

        #pragma unroll
        for (int kk = 0; kk < 2; ++kk) {
            half8 aj[4], bi[4];
            #pragma unroll
            for (int jt = 0; jt < 4; ++jt) {
                const int r = wc * 64 + jt * 16 + l15;
                aj[jt] = *(const half8*)&Bs[r * 64 + (((kk * 4 + grp) ^ (r & 7)) << 3)];
            }
            #pragma unroll
            for (int it = 0; it < 4; ++it) {
                const int r = wr * 64 + it * 16 + l15;
                bi[it] = *(const half8*)&As[r * 64 + (((kk * 4 + grp) ^ (r & 7)) << 3)];
            }
            #pragma unroll
            for (int jt = 0; jt < 4; ++jt)
                #pragma unroll
                for (int it = 0; it < 4; ++it)
                    acc[jt][it] = __builtin_amdgcn_mfma_f32_16x16x32_f16(
                        aj[jt], bi[it], acc[jt][it], 0, 0, 0);
        }
        __syncthreads();
    }

    // ---- epilogue: one u32 mask load per it, exp/fma, reduce over grp ----
    const int    mrow0 = i0 + wr * 64 + l15;
    const size_t mcol  = (size_t)(bx >> 1) * 64 + (bx & 1) * 32 + wc * 16 + grp * 4;

    #pragma unroll
    for (int it = 0; it < 4; ++it) {
        const int i = mrow0 + it * 16;
        const unsigned mw = *(const unsigned*)(M + (size_t)i * 1024 + mcol);
        float negp = 0.f, posp = 0.f, np = 0.f;
        #pragma unroll
        for (int jt = 0; jt < 4; ++jt) {
            const unsigned byv = (mw >> (8 * jt)) & 0xFFu;
            #pragma unroll
            for (int e = 0; e < 4; ++e) {
                const float cs = acc[jt][it][e] * INV_T;
                const float pf = (float)((byv >> e) & 1u);
                const float nf = (float)((byv >> (4 + e)) & 1u);
                negp = fmaf(__expf(cs), nf, negp);
                posp = fmaf(cs, pf, posp);
                np  += pf;
            }
        }
        negp += __shfl_xor(negp, 16, 64);
        posp += __shfl_xor(posp, 16, 64);
        np   += __shfl_xor(np,   16, 64);
        negp += __shfl_xor(negp, 32, 64);
        posp += __shfl_xor(posp, 32, 64);
        np   += __shfl_xor(np,   32, 64);
        if (grp == 0) {
            atomicAdd(&accum[i], negp);
            atomicAdd(&accum[N_ROWS + i], posp);
            atomicAdd(&accum[2 * N_ROWS + i], np);
        }
    }
}

// ---------------------------------------------------------------------------
// final_k: reduction over rows -> scalar loss
// ---------------------------------------------------------------------------
__global__ __launch_bounds__(256) void final_k(const float* __restrict__ accum,
                                               float* __restrict__ out) {
    const int t = threadIdx.x;
    float s = 0.f;
    for (int i = t; i < N_ROWS; i += 256) {
        float neg  = accum[i];
        float posc = accum[N_ROWS + i];
        float np   = accum[2 * N_ROWS + i];
        float term = (np > 0.f) ? (posc - np * logf(fmaxf(neg, 1e-30f))) / np : 0.f;
        s += term;
    }
    #pragma unroll
    for (int off = 32; off > 0; off >>= 1) s += __shfl_xor(s, off, 64);
    __shared__ float wsum[4];
    if ((t & 63) == 0) wsum[t >> 6] = s;
    __syncthreads();
    if (t == 0) {
        float tot = wsum[0] + wsum[1] + wsum[2] + wsum[3];
        out[0] = -tot / (float)N_ROWS;
    }
}

// ---------------------------------------------------------------------------
// ws layout: fnh 2 MB | accum 64 KB | M 4 MB  (~6.1 MB total; fits the
// budget the packed-mask path already used in rounds 3/5).
// ---------------------------------------------------------------------------
extern "C" void kernel_launch(void* const* d_in, const int* in_sizes, int n_in,
                              void* d_out, int out_size, void* d_ws, size_t ws_size,
                              hipStream_t stream) {
    const float* feat = (const float*)d_in[0];
    const float* pm   = (const float*)d_in[1];
    const float* nm   = (const float*)d_in[2];
    float* out = (float*)d_out;

    const size_t FNH_B = (size_t)N_ROWS * D_DIM * sizeof(_Float16);  // 2 MB
    const size_t ACC_B = 65536;

    _Float16* fnh = (_Float16*)d_ws;
    float* accum  = (float*)((char*)d_ws + FNH_B);
    u8* M         = (u8*)((char*)d_ws + FNH_B + ACC_B);              // 4 MB

    prep_k<<<N_ROWS / 2, 256, 0, stream>>>(feat, pm, nm, fnh, M, accum);

    dim3 grid(N_ROWS / 128, N_ROWS / 128);
    fused_k<<<grid, 256, 0, stream>>>(fnh, M, accum);

    final_k<<<1, 256, 0, stream>>>(accum, out);
}